// Round 1
// baseline (1714.334 us; speedup 1.0000x reference)
//
#include <hip/hip_runtime.h>
#include <hip/hip_bf16.h>
#include <math.h>

#define GN 19            // graph nodes
#define GNN (GN*GN)      // 361
#define GE 64            // graph embed / hidden
#define LH 64            // lstm hidden
#define BB 256           // batch
#define TT 256           // seq len

__device__ __forceinline__ float sigmoidf(float x) {
    return 1.0f / (1.0f + __expf(-x));
}

// ---------------------------------------------------------------------------
// Kernel A: graph encoder.  One wave (64 threads) per block; thread t owns
// output column t of every intermediate (GH == GE == 64 == wave size).
// Grid-stride over graphs to amortize register-resident weight rows.
// ---------------------------------------------------------------------------
__global__ __launch_bounds__(64) void encoder_kernel(
    const float* __restrict__ conn,   // (num_graphs, 19, 19)
    const int*   __restrict__ mask,   // (num_graphs)
    const float* __restrict__ w1_w,   // (64, 19)
    const float* __restrict__ w1_b,   // (64)
    const float* __restrict__ w2_w,   // (64, 64)
    const float* __restrict__ w2_b,   // (64)
    float* __restrict__ emb,          // (num_graphs, 64)
    int num_graphs)
{
    __shared__ float A[GNN];
    __shared__ float An[GNN];
    __shared__ float dis[GN];
    __shared__ float X1[GN * 64];     // 19 x 64

    const int t = threadIdx.x;        // 0..63

    // Per-thread weight rows (registers).
    float w1r[GN];
    #pragma unroll
    for (int j = 0; j < GN; ++j) w1r[j] = w1_w[t * GN + j];
    float w2r[64];
    {
        const float4* p = (const float4*)(w2_w + t * 64);
        #pragma unroll
        for (int j = 0; j < 16; ++j) ((float4*)w2r)[j] = p[j];
    }
    const float b1t = w1_b[t];
    const float b2t = w2_b[t];

    #pragma unroll 1
    for (int g = blockIdx.x; g < num_graphs; g += gridDim.x) {
        const float* Ag = conn + (size_t)g * GNN;

        // Stage A (coalesced).
        for (int k = t; k < GNN; k += 64) A[k] = Ag[k];
        __syncthreads();

        // Degree of A + I -> dis = deg^-0.5
        if (t < GN) {
            float s = 1.0f;   // self loop
            #pragma unroll
            for (int j = 0; j < GN; ++j) s += A[t * GN + j];
            dis[t] = rsqrtf(fmaxf(s, 1e-6f));
        }
        __syncthreads();

        // An = (A + I) * dis_i * dis_j
        for (int k = t; k < GNN; k += 64) {
            int i = k / GN;
            int j = k - i * GN;
            float v = A[k] + (i == j ? 1.0f : 0.0f);
            An[k] = v * dis[i] * dis[j];
        }
        __syncthreads();

        // H1[:,t] = A @ w1_w.T[:,t] + b1[t]   (uses RAW A per reference)
        float h1[GN];
        #pragma unroll
        for (int i = 0; i < GN; ++i) {
            float acc = b1t;
            #pragma unroll
            for (int j = 0; j < GN; ++j) acc += A[i * GN + j] * w1r[j];
            h1[i] = acc;
        }
        // X1[:,t] = relu(An @ H1[:,t]) -> LDS (needed cross-thread)
        #pragma unroll
        for (int i = 0; i < GN; ++i) {
            float acc = 0.0f;
            #pragma unroll
            for (int j = 0; j < GN; ++j) acc += An[i * GN + j] * h1[j];
            X1[i * 64 + t] = fmaxf(acc, 0.0f);
        }
        __syncthreads();

        // H2[:,t] = X1 @ w2_w.T[:,t] + b2[t]
        float h2[GN];
        #pragma unroll
        for (int i = 0; i < GN; ++i) {
            float acc = b2t;
            const float4* xv = (const float4*)(&X1[i * 64]);
            #pragma unroll
            for (int j = 0; j < 16; ++j) {
                float4 x4 = xv[j];
                acc += x4.x * w2r[4*j]   + x4.y * w2r[4*j+1]
                     + x4.z * w2r[4*j+2] + x4.w * w2r[4*j+3];
            }
            h2[i] = acc;
        }
        // X2 = relu(An @ H2); emb[t] = mean_i X2[i,t] * mask
        float s = 0.0f;
        #pragma unroll
        for (int i = 0; i < GN; ++i) {
            float acc = 0.0f;
            #pragma unroll
            for (int j = 0; j < GN; ++j) acc += An[i * GN + j] * h2[j];
            s += fmaxf(acc, 0.0f);
        }
        float mf = (float)mask[g];
        emb[(size_t)g * 64 + t] = s * (1.0f / 19.0f) * mf;
        __syncthreads();   // LDS reused next graph
    }
}

// ---------------------------------------------------------------------------
// Kernel B: fused 2-layer LSTM + FC head.  One block per batch element
// (persistent), 256 threads; thread i owns gate-row i of both layers with
// all four weight rows in registers (256 VGPRs).  h broadcast via LDS.
// ---------------------------------------------------------------------------
__global__ __launch_bounds__(256, 1) void lstm_head_kernel(
    const float* __restrict__ emb,    // (B, T, 64)
    const int*   __restrict__ mask,   // (B, T)
    const float* __restrict__ Wih0, const float* __restrict__ Whh0,
    const float* __restrict__ bih0, const float* __restrict__ bhh0,
    const float* __restrict__ Wih1, const float* __restrict__ Whh1,
    const float* __restrict__ bih1, const float* __restrict__ bhh1,
    const float* __restrict__ fc1_w, const float* __restrict__ fc1_b,
    const float* __restrict__ fc2_w, const float* __restrict__ fc2_b,
    float* __restrict__ out)          // (B, 2)
{
    __shared__ float xseq[TT * LH];   // 64 KB: whole input sequence
    __shared__ float h0s[LH];
    __shared__ float h1s[LH];
    __shared__ float gates[4 * LH];
    __shared__ float hlast[LH];
    __shared__ float hfc[32];
    __shared__ int   msum[256];
    __shared__ int   lastidx_s;

    const int b = blockIdx.x;
    const int i = threadIdx.x;

    // Stage the whole emb sequence for this batch element into LDS.
    {
        const float4* src = (const float4*)(emb + (size_t)b * TT * LH);
        float4* dst = (float4*)xseq;
        #pragma unroll
        for (int k = 0; k < (TT * LH / 4) / 256; ++k)
            dst[k * 256 + i] = src[k * 256 + i];
    }

    // last_idx = clip(sum(mask) - 1, 0, T-1)
    msum[i] = mask[b * TT + i];
    if (i < LH) { h0s[i] = 0.0f; h1s[i] = 0.0f; }

    // Weight rows into registers.
    float wx0[64], wh0[64], wx1[64], wh1[64];
    {
        const float4* p0 = (const float4*)(Wih0 + i * 64);
        const float4* p1 = (const float4*)(Whh0 + i * 64);
        const float4* p2 = (const float4*)(Wih1 + i * 64);
        const float4* p3 = (const float4*)(Whh1 + i * 64);
        #pragma unroll
        for (int j = 0; j < 16; ++j) {
            ((float4*)wx0)[j] = p0[j];
            ((float4*)wh0)[j] = p1[j];
            ((float4*)wx1)[j] = p2[j];
            ((float4*)wh1)[j] = p3[j];
        }
    }
    const float bias0 = bih0[i] + bhh0[i];
    const float bias1 = bih1[i] + bhh1[i];

    __syncthreads();
    if (i == 0) {
        int len = 0;
        for (int t = 0; t < TT; ++t) len += msum[t];
        int li = len - 1;
        if (li < 0) li = 0;
        if (li > TT - 1) li = TT - 1;
        lastidx_s = li;
    }
    __syncthreads();
    const int lastidx = lastidx_s;

    float c0 = 0.0f, c1 = 0.0f;   // live only in threads i < 64

    #pragma unroll 1
    for (int t = 0; t < TT; ++t) {
        // ---- layer 0 gate i ----
        float acc = bias0;
        {
            const float4* xv = (const float4*)(xseq + t * LH);
            const float4* hv = (const float4*)h0s;
            #pragma unroll
            for (int j = 0; j < 16; ++j) {
                float4 x4 = xv[j];
                float4 h4 = hv[j];
                acc += x4.x * wx0[4*j]   + x4.y * wx0[4*j+1]
                     + x4.z * wx0[4*j+2] + x4.w * wx0[4*j+3];
                acc += h4.x * wh0[4*j]   + h4.y * wh0[4*j+1]
                     + h4.z * wh0[4*j+2] + h4.w * wh0[4*j+3];
            }
        }
        gates[i] = acc;
        __syncthreads();
        if (i < LH) {
            float ig = gates[i], fg = gates[64 + i];
            float gg = gates[128 + i], og = gates[192 + i];
            c0 = sigmoidf(fg) * c0 + sigmoidf(ig) * tanhf(gg);
            h0s[i] = sigmoidf(og) * tanhf(c0);
        }
        __syncthreads();

        // ---- layer 1 gate i ----
        float acc1 = bias1;
        {
            const float4* xv = (const float4*)h0s;
            const float4* hv = (const float4*)h1s;
            #pragma unroll
            for (int j = 0; j < 16; ++j) {
                float4 x4 = xv[j];
                float4 h4 = hv[j];
                acc1 += x4.x * wx1[4*j]   + x4.y * wx1[4*j+1]
                      + x4.z * wx1[4*j+2] + x4.w * wx1[4*j+3];
                acc1 += h4.x * wh1[4*j]   + h4.y * wh1[4*j+1]
                      + h4.z * wh1[4*j+2] + h4.w * wh1[4*j+3];
            }
        }
        gates[i] = acc1;
        __syncthreads();
        if (i < LH) {
            float ig = gates[i], fg = gates[64 + i];
            float gg = gates[128 + i], og = gates[192 + i];
            c1 = sigmoidf(fg) * c1 + sigmoidf(ig) * tanhf(gg);
            float hn = sigmoidf(og) * tanhf(c1);
            h1s[i] = hn;
            if (t == lastidx) hlast[i] = hn;
        }
        __syncthreads();
    }

    // ---- head: fc1 (64->32) relu, fc2 (32->2) ----
    if (i < 32) {
        float acc = fc1_b[i];
        #pragma unroll
        for (int j = 0; j < 64; ++j) acc += fc1_w[i * 64 + j] * hlast[j];
        hfc[i] = fmaxf(acc, 0.0f);
    }
    __syncthreads();
    if (i < 2) {
        float acc = fc2_b[i];
        #pragma unroll
        for (int j = 0; j < 32; ++j) acc += fc2_w[i * 32 + j] * hfc[j];
        out[b * 2 + i] = acc;
    }
}

// ---------------------------------------------------------------------------
extern "C" void kernel_launch(void* const* d_in, const int* in_sizes, int n_in,
                              void* d_out, int out_size, void* d_ws, size_t ws_size,
                              hipStream_t stream)
{
    const float* conn  = (const float*)d_in[0];
    const int*   mask  = (const int*)  d_in[1];
    const float* w1_w  = (const float*)d_in[2];
    const float* w1_b  = (const float*)d_in[3];
    const float* w2_w  = (const float*)d_in[4];
    const float* w2_b  = (const float*)d_in[5];
    const float* Wih0  = (const float*)d_in[6];
    const float* Whh0  = (const float*)d_in[7];
    const float* bih0  = (const float*)d_in[8];
    const float* bhh0  = (const float*)d_in[9];
    const float* Wih1  = (const float*)d_in[10];
    const float* Whh1  = (const float*)d_in[11];
    const float* bih1  = (const float*)d_in[12];
    const float* bhh1  = (const float*)d_in[13];
    const float* fc1_w = (const float*)d_in[14];
    const float* fc1_b = (const float*)d_in[15];
    const float* fc2_w = (const float*)d_in[16];
    const float* fc2_b = (const float*)d_in[17];

    float* out = (float*)d_out;
    float* emb = (float*)d_ws;            // (B*T, 64) fp32 = 16.8 MB

    const int num_graphs = BB * TT;       // 65536

    encoder_kernel<<<8192, 64, 0, stream>>>(
        conn, mask, w1_w, w1_b, w2_w, w2_b, emb, num_graphs);

    lstm_head_kernel<<<BB, 256, 0, stream>>>(
        emb, mask, Wih0, Whh0, bih0, bhh0, Wih1, Whh1, bih1, bhh1,
        fc1_w, fc1_b, fc2_w, fc2_b, out);
}

// Round 2
// 1011.996 us; speedup vs baseline: 1.6940x; 1.6940x over previous
//
#include <hip/hip_runtime.h>
#include <hip/hip_bf16.h>
#include <math.h>

#define GN 19            // graph nodes
#define LDA 68           // padded LDS row stride (floats); rows stay 16B aligned
#define BB 256
#define TT 256

typedef short short8 __attribute__((ext_vector_type(8)));
typedef float f4 __attribute__((ext_vector_type(4)));

// RNE float -> bf16 (finite inputs)
__device__ __forceinline__ short bf(float x) {
    union { float f; unsigned u; } c; c.f = x;
    unsigned r = c.u + 0x7FFFu + ((c.u >> 16) & 1u);
    return (short)(r >> 16);
}

__device__ __forceinline__ float rl(float v, int j) {
    return __int_as_float(__builtin_amdgcn_readlane(__float_as_int(v), j));
}
__device__ __forceinline__ float fexp2(float x) { return __builtin_amdgcn_exp2f(x); }
__device__ __forceinline__ float frcp(float x)  { return __builtin_amdgcn_rcpf(x); }
__device__ __forceinline__ float sigm(float x)  { return frcp(1.f + fexp2(-1.4426950408889634f * x)); }
__device__ __forceinline__ float tanha(float x) { float e = fexp2(2.8853900817779268f * x); return 1.f - 2.f * frcp(e + 1.f); }

// ---------------------------------------------------------------------------
// Kernel A: graph encoder via bf16 MFMA (16x16x32).  One wave per block, one
// graph at a time, grid-stride.  MFMA layouts (gfx950, verified in guide):
//   A-op: A[m=lane&15][k=quad*8+j]; B-op: B[k=quad*8+j][n=lane&15];
//   C/D : D[row=quad*4+reg][col=lane&15].
// All K/M padding rows/cols are forced to zero (dis[19..31]=0 handles An).
// ---------------------------------------------------------------------------
__global__ __launch_bounds__(64) void encoder_mfma(
    const float* __restrict__ conn,   // (G,19,19)
    const int*   __restrict__ mask,   // (G)
    const float* __restrict__ w1_w,   // (64,19)
    const float* __restrict__ w1_b,   // (64)
    const float* __restrict__ w2_w,   // (64,64)
    const float* __restrict__ w2_b,   // (64)
    float* __restrict__ emb,          // (G,64)
    int num_graphs)
{
    __shared__ float S[32 * LDA];   // A / H1 / X1 / H2 round-trip buffer
    __shared__ float dis[32];
    __shared__ float ps[256];

    const int t = threadIdx.x;
    const int l15 = t & 15;
    const int quad = t >> 4;

    // ---- weight fragments + biases (once per block) ----
    short8 w1F[4];
    #pragma unroll
    for (int nt = 0; nt < 4; ++nt) {
        int n = nt * 16 + l15;
        #pragma unroll
        for (int j = 0; j < 8; ++j) {
            int k = quad * 8 + j;
            float v = 0.f;
            if (k < GN) v = w1_w[n * GN + k];
            w1F[nt][j] = bf(v);
        }
    }
    short8 w2F[2][4];
    #pragma unroll
    for (int kt = 0; kt < 2; ++kt)
        #pragma unroll
        for (int nt = 0; nt < 4; ++nt) {
            int n = nt * 16 + l15;
            #pragma unroll
            for (int j = 0; j < 8; ++j) {
                int k = kt * 32 + quad * 8 + j;
                w2F[kt][nt][j] = bf(w2_w[n * 64 + k]);
            }
        }
    float b1v[4], b2v[4];
    #pragma unroll
    for (int nt = 0; nt < 4; ++nt) {
        b1v[nt] = w1_b[nt * 16 + l15];
        b2v[nt] = w2_b[nt * 16 + l15];
    }

    #pragma unroll 1
    for (int g = blockIdx.x; g < num_graphs; g += gridDim.x) {
        const float* Ag = conn + (size_t)g * (GN * GN);

        // zero S[0..31][0..31]
        #pragma unroll
        for (int i = 0; i < 4; ++i) {
            int s = t + 64 * i;          // 256 float4 slots
            int row = s >> 3, c4 = s & 7;
            f4 z = {0.f, 0.f, 0.f, 0.f};
            *(f4*)&S[row * LDA + c4 * 4] = z;
        }
        // stage A (361 floats)
        #pragma unroll
        for (int i = 0; i < 6; ++i) {
            int e = t + 64 * i;
            if (e < GN * GN) {
                int r = e / GN, c = e - r * GN;
                S[r * LDA + c] = Ag[e];
            }
        }
        __syncthreads();

        // degree -> dis (lanes 0..18), zero pad 19..31
        if (t < 32) {
            float dv = 0.f;
            if (t < GN) {
                float d = 1.0f;   // self loop
                #pragma unroll
                for (int c4 = 0; c4 < 8; ++c4) {
                    f4 v = *(f4*)&S[t * LDA + c4 * 4];
                    d += v.x + v.y + v.z + v.w;
                }
                dv = rsqrtf(d);
            }
            dis[t] = dv;
        }
        __syncthreads();

        // pack aF (raw A) and anF (normalized adjacency), 2 M-tiles
        float dk[8];
        {
            f4 v0 = *(f4*)&dis[quad * 8];
            f4 v1 = *(f4*)&dis[quad * 8 + 4];
            dk[0]=v0.x; dk[1]=v0.y; dk[2]=v0.z; dk[3]=v0.w;
            dk[4]=v1.x; dk[5]=v1.y; dk[6]=v1.z; dk[7]=v1.w;
        }
        short8 aF[2], anF[2];
        #pragma unroll
        for (int mt = 0; mt < 2; ++mt) {
            int m = l15 + 16 * mt;
            float dm = dis[m];
            f4 v0 = *(f4*)&S[m * LDA + quad * 8];
            f4 v1 = *(f4*)&S[m * LDA + quad * 8 + 4];
            float av[8] = {v0.x, v0.y, v0.z, v0.w, v1.x, v1.y, v1.z, v1.w};
            #pragma unroll
            for (int j = 0; j < 8; ++j) {
                int k = quad * 8 + j;
                float an = (av[j] + (m == k ? 1.f : 0.f)) * dm * dk[j];
                aF[mt][j]  = bf(av[j]);
                anF[mt][j] = bf(an);
            }
        }
        __syncthreads();

        // MFMA1: H1 = A @ W1^T + b1  -> S
        #pragma unroll
        for (int mt = 0; mt < 2; ++mt)
            #pragma unroll
            for (int nt = 0; nt < 4; ++nt) {
                float bb = b1v[nt];
                f4 c = {bb, bb, bb, bb};
                c = __builtin_amdgcn_mfma_f32_16x16x32_bf16(aF[mt], w1F[nt], c, 0, 0, 0);
                int col = nt * 16 + l15;
                #pragma unroll
                for (int r = 0; r < 4; ++r)
                    S[(mt * 16 + quad * 4 + r) * LDA + col] = c[r];
            }
        __syncthreads();

        // pack H1 as B-op (zero rows k>=19: they hold bias garbage)
        short8 hF[4];
        #pragma unroll
        for (int nt = 0; nt < 4; ++nt) {
            int col = nt * 16 + l15;
            #pragma unroll
            for (int j = 0; j < 8; ++j) {
                int k = quad * 8 + j;
                float v = (k < GN) ? S[k * LDA + col] : 0.f;
                hF[nt][j] = bf(v);
            }
        }
        __syncthreads();

        // MFMA2: X1 = relu(An @ H1) -> S
        #pragma unroll
        for (int mt = 0; mt < 2; ++mt)
            #pragma unroll
            for (int nt = 0; nt < 4; ++nt) {
                f4 c = {0.f, 0.f, 0.f, 0.f};
                c = __builtin_amdgcn_mfma_f32_16x16x32_bf16(anF[mt], hF[nt], c, 0, 0, 0);
                int col = nt * 16 + l15;
                #pragma unroll
                for (int r = 0; r < 4; ++r)
                    S[(mt * 16 + quad * 4 + r) * LDA + col] = fmaxf(c[r], 0.f);
            }
        __syncthreads();

        // pack X1 as A-op (rows>=19 already zero), K=64 -> 2 K-tiles
        short8 xF[2][2];
        #pragma unroll
        for (int mt = 0; mt < 2; ++mt) {
            int m = l15 + 16 * mt;
            #pragma unroll
            for (int kt = 0; kt < 2; ++kt) {
                f4 v0 = *(f4*)&S[m * LDA + kt * 32 + quad * 8];
                f4 v1 = *(f4*)&S[m * LDA + kt * 32 + quad * 8 + 4];
                xF[mt][kt][0] = bf(v0.x); xF[mt][kt][1] = bf(v0.y);
                xF[mt][kt][2] = bf(v0.z); xF[mt][kt][3] = bf(v0.w);
                xF[mt][kt][4] = bf(v1.x); xF[mt][kt][5] = bf(v1.y);
                xF[mt][kt][6] = bf(v1.z); xF[mt][kt][7] = bf(v1.w);
            }
        }
        __syncthreads();

        // MFMA3: H2 = X1 @ W2^T + b2 -> S
        #pragma unroll
        for (int mt = 0; mt < 2; ++mt)
            #pragma unroll
            for (int nt = 0; nt < 4; ++nt) {
                float bb = b2v[nt];
                f4 c = {bb, bb, bb, bb};
                c = __builtin_amdgcn_mfma_f32_16x16x32_bf16(xF[mt][0], w2F[0][nt], c, 0, 0, 0);
                c = __builtin_amdgcn_mfma_f32_16x16x32_bf16(xF[mt][1], w2F[1][nt], c, 0, 0, 0);
                int col = nt * 16 + l15;
                #pragma unroll
                for (int r = 0; r < 4; ++r)
                    S[(mt * 16 + quad * 4 + r) * LDA + col] = c[r];
            }
        __syncthreads();

        // pack H2 as B-op (zero rows k>=19)
        #pragma unroll
        for (int nt = 0; nt < 4; ++nt) {
            int col = nt * 16 + l15;
            #pragma unroll
            for (int j = 0; j < 8; ++j) {
                int k = quad * 8 + j;
                float v = (k < GN) ? S[k * LDA + col] : 0.f;
                hF[nt][j] = bf(v);
            }
        }

        // MFMA4: X2 = relu(An @ H2); column means -> emb
        float cs[4];
        #pragma unroll
        for (int nt = 0; nt < 4; ++nt) cs[nt] = 0.f;
        #pragma unroll
        for (int mt = 0; mt < 2; ++mt)
            #pragma unroll
            for (int nt = 0; nt < 4; ++nt) {
                f4 c = {0.f, 0.f, 0.f, 0.f};
                c = __builtin_amdgcn_mfma_f32_16x16x32_bf16(anF[mt], hF[nt], c, 0, 0, 0);
                if (mt == 0) {
                    cs[nt] += fmaxf(c[0], 0.f) + fmaxf(c[1], 0.f)
                            + fmaxf(c[2], 0.f) + fmaxf(c[3], 0.f);
                } else if (quad == 0) {   // rows 16,17,18 valid
                    cs[nt] += fmaxf(c[0], 0.f) + fmaxf(c[1], 0.f) + fmaxf(c[2], 0.f);
                }
            }
        __syncthreads();
        #pragma unroll
        for (int nt = 0; nt < 4; ++nt)
            ps[quad * 64 + nt * 16 + l15] = cs[nt];
        __syncthreads();
        float tot = ps[t] + ps[64 + t] + ps[128 + t] + ps[192 + t];
        float mf = (float)mask[g];
        emb[(size_t)g * 64 + t] = tot * (1.f / 19.f) * mf;
        __syncthreads();
    }
}

// ---------------------------------------------------------------------------
// Kernel B: LSTM layer 0 (persistent, one block per batch element).
// Thread tid owns gate-row tid (wave w = gate type i/f/g/o, lane l = h-dim).
// x-part: wave-uniform s_loads of emb row; h-part: readlane (no DS pipe).
// h,c replicated per wave; gate exchange via 256-float LDS + 2 barriers.
// ---------------------------------------------------------------------------
__global__ __launch_bounds__(256, 1) void lstm_l0(
    const float* __restrict__ emb,    // (B*T, 64)
    const float* __restrict__ Wih0, const float* __restrict__ Whh0,
    const float* __restrict__ bih0, const float* __restrict__ bhh0,
    float* __restrict__ h0seq)        // (B*T, 64)
{
    __shared__ float gs[256];
    const int tid = threadIdx.x;
    const int w = tid >> 6, l = tid & 63;
    const int b = blockIdx.x;

    float wi[64], wh[64];
    {
        const float4* p = (const float4*)(Wih0 + tid * 64);
        const float4* q = (const float4*)(Whh0 + tid * 64);
        #pragma unroll
        for (int j = 0; j < 16; ++j) {
            ((float4*)wi)[j] = p[j];
            ((float4*)wh)[j] = q[j];
        }
    }
    const float bias = bih0[tid] + bhh0[tid];

    float h = 0.f, c = 0.f;
    const float* __restrict__ eb = emb + (size_t)b * TT * 64;

    #pragma unroll 1
    for (int t = 0; t < TT; ++t) {
        const float* __restrict__ er = eb + t * 64;
        float a0 = bias, a1 = 0.f, a2 = 0.f, a3 = 0.f;
        // h-part first (readlane), giving the uniform er loads time to land
        #pragma unroll
        for (int j = 0; j < 64; j += 4) {
            a0 = fmaf(rl(h, j),     wh[j],     a0);
            a1 = fmaf(rl(h, j + 1), wh[j + 1], a1);
            a2 = fmaf(rl(h, j + 2), wh[j + 2], a2);
            a3 = fmaf(rl(h, j + 3), wh[j + 3], a3);
        }
        #pragma unroll
        for (int j = 0; j < 64; j += 4) {
            a0 = fmaf(er[j],     wi[j],     a0);
            a1 = fmaf(er[j + 1], wi[j + 1], a1);
            a2 = fmaf(er[j + 2], wi[j + 2], a2);
            a3 = fmaf(er[j + 3], wi[j + 3], a3);
        }
        gs[tid] = (a0 + a1) + (a2 + a3);
        __syncthreads();
        float gi = gs[l], gf = gs[64 + l], gg = gs[128 + l], go = gs[192 + l];
        __syncthreads();
        c = sigm(gf) * c + sigm(gi) * tanha(gg);
        h = sigm(go) * tanha(c);
        if (w == 0) h0seq[((size_t)b * TT + t) * 64 + l] = h;
    }
}

// ---------------------------------------------------------------------------
// Kernel C: LSTM layer 1 + FC head.  Same structure as layer 0; x-part reads
// h0seq rows (uniform).  Captures h at last_idx, then fc1->relu->fc2.
// ---------------------------------------------------------------------------
__global__ __launch_bounds__(256, 1) void lstm_l1_head(
    const float* __restrict__ h0seq,  // (B*T, 64)
    const int*   __restrict__ mask,   // (B, T)
    const float* __restrict__ Wih1, const float* __restrict__ Whh1,
    const float* __restrict__ bih1, const float* __restrict__ bhh1,
    const float* __restrict__ fc1_w, const float* __restrict__ fc1_b,
    const float* __restrict__ fc2_w, const float* __restrict__ fc2_b,
    float* __restrict__ out)          // (B, 2)
{
    __shared__ float gs[256];
    __shared__ int li_s;
    const int tid = threadIdx.x;
    const int w = tid >> 6, l = tid & 63;
    const int b = blockIdx.x;

    float wi[64], wh[64];
    {
        const float4* p = (const float4*)(Wih1 + tid * 64);
        const float4* q = (const float4*)(Whh1 + tid * 64);
        #pragma unroll
        for (int j = 0; j < 16; ++j) {
            ((float4*)wi)[j] = p[j];
            ((float4*)wh)[j] = q[j];
        }
    }
    const float bias = bih1[tid] + bhh1[tid];

    // last_idx = clip(sum(mask)-1, 0, T-1)
    gs[tid] = (float)mask[b * TT + tid];
    __syncthreads();
    if (tid == 0) {
        float s = 0.f;
        for (int t = 0; t < TT; ++t) s += gs[t];
        int li = (int)s - 1;
        li = li < 0 ? 0 : (li > TT - 1 ? TT - 1 : li);
        li_s = li;
    }
    __syncthreads();
    const int lastidx = li_s;

    float h = 0.f, c = 0.f, hl = 0.f;
    const float* __restrict__ xb = h0seq + (size_t)b * TT * 64;

    #pragma unroll 1
    for (int t = 0; t < TT; ++t) {
        const float* __restrict__ xr = xb + t * 64;
        float a0 = bias, a1 = 0.f, a2 = 0.f, a3 = 0.f;
        #pragma unroll
        for (int j = 0; j < 64; j += 4) {
            a0 = fmaf(rl(h, j),     wh[j],     a0);
            a1 = fmaf(rl(h, j + 1), wh[j + 1], a1);
            a2 = fmaf(rl(h, j + 2), wh[j + 2], a2);
            a3 = fmaf(rl(h, j + 3), wh[j + 3], a3);
        }
        #pragma unroll
        for (int j = 0; j < 64; j += 4) {
            a0 = fmaf(xr[j],     wi[j],     a0);
            a1 = fmaf(xr[j + 1], wi[j + 1], a1);
            a2 = fmaf(xr[j + 2], wi[j + 2], a2);
            a3 = fmaf(xr[j + 3], wi[j + 3], a3);
        }
        gs[tid] = (a0 + a1) + (a2 + a3);
        __syncthreads();
        float gi = gs[l], gf = gs[64 + l], gg = gs[128 + l], go = gs[192 + l];
        __syncthreads();
        c = sigm(gf) * c + sigm(gi) * tanha(gg);
        h = sigm(go) * tanha(c);
        if (t == lastidx) hl = h;
    }

    // head: fc1 (64->32) relu, fc2 (32->2); wave 0 only
    __syncthreads();
    if (w == 0 && l < 32) {
        float acc = fc1_b[l];
        const float* fw = fc1_w + l * 64;
        #pragma unroll
        for (int j = 0; j < 64; ++j)
            acc = fmaf(fw[j], rl(hl, j), acc);
        gs[l] = fmaxf(acc, 0.f);
    }
    __syncthreads();
    if (w == 0 && l < 2) {
        float acc = fc2_b[l];
        #pragma unroll
        for (int j = 0; j < 32; ++j)
            acc = fmaf(fc2_w[l * 32 + j], gs[j], acc);
        out[b * 2 + l] = acc;
    }
}

// ---------------------------------------------------------------------------
extern "C" void kernel_launch(void* const* d_in, const int* in_sizes, int n_in,
                              void* d_out, int out_size, void* d_ws, size_t ws_size,
                              hipStream_t stream)
{
    const float* conn  = (const float*)d_in[0];
    const int*   mask  = (const int*)  d_in[1];
    const float* w1_w  = (const float*)d_in[2];
    const float* w1_b  = (const float*)d_in[3];
    const float* w2_w  = (const float*)d_in[4];
    const float* w2_b  = (const float*)d_in[5];
    const float* Wih0  = (const float*)d_in[6];
    const float* Whh0  = (const float*)d_in[7];
    const float* bih0  = (const float*)d_in[8];
    const float* bhh0  = (const float*)d_in[9];
    const float* Wih1  = (const float*)d_in[10];
    const float* Whh1  = (const float*)d_in[11];
    const float* bih1  = (const float*)d_in[12];
    const float* bhh1  = (const float*)d_in[13];
    const float* fc1_w = (const float*)d_in[14];
    const float* fc1_b = (const float*)d_in[15];
    const float* fc2_w = (const float*)d_in[16];
    const float* fc2_b = (const float*)d_in[17];

    float* out = (float*)d_out;
    float* emb   = (float*)d_ws;                         // 16.8 MB
    float* h0seq = (float*)d_ws + (size_t)BB * TT * 64;  // +16.8 MB

    const int num_graphs = BB * TT;

    encoder_mfma<<<8192, 64, 0, stream>>>(
        conn, mask, w1_w, w1_b, w2_w, w2_b, emb, num_graphs);

    lstm_l0<<<BB, 256, 0, stream>>>(emb, Wih0, Whh0, bih0, bhh0, h0seq);

    lstm_l1_head<<<BB, 256, 0, stream>>>(
        h0seq, mask, Wih1, Whh1, bih1, bhh1,
        fc1_w, fc1_b, fc2_w, fc2_b, out);
}

// Round 3
// 883.911 us; speedup vs baseline: 1.9395x; 1.1449x over previous
//
#include <hip/hip_runtime.h>
#include <hip/hip_bf16.h>
#include <math.h>

#define GN 19            // graph nodes
#define BB 256
#define TT 256

typedef short short8 __attribute__((ext_vector_type(8)));
typedef float f4 __attribute__((ext_vector_type(4)));

union Frag { int i[4]; short8 s; };

// packed RNE float pair -> bf16 pair (v_cvt_pk_bf16_f32 on gfx950)
__device__ __forceinline__ int pkbf(float a, float b) {
    __hip_bfloat162 h2 = __float22bfloat162_rn(make_float2(a, b));
    union { __hip_bfloat162 h; int i; } u; u.h = h2; return u.i;
}

__device__ __forceinline__ float rl(float v, int j) {
    return __int_as_float(__builtin_amdgcn_readlane(__float_as_int(v), j));
}
__device__ __forceinline__ float fexp2(float x) { return __builtin_amdgcn_exp2f(x); }
__device__ __forceinline__ float frcp(float x)  { return __builtin_amdgcn_rcpf(x); }
__device__ __forceinline__ float sigm(float x)  { return frcp(1.f + fexp2(-1.4426950408889634f * x)); }
__device__ __forceinline__ float tanha(float x) { float e = fexp2(2.8853900817779268f * x); return 1.f - 2.f * frcp(e + 1.f); }

// ---------------------------------------------------------------------------
// Kernel A: graph encoder via bf16 MFMA (16x16x32).  One wave per block,
// grid-stride over graphs.  Single LDS buffer S reused as:
//   A (32 x 68 row-major) -> H1^T (64 x 36, col-major) -> X1 (32 x 68)
//   -> H2^T (64 x 36).  Transposed H stores make B-operand repacks b128.
// ---------------------------------------------------------------------------
__global__ __launch_bounds__(64) void encoder_mfma(
    const float* __restrict__ conn,   // (G,19,19)
    const int*   __restrict__ mask,   // (G)
    const float* __restrict__ w1_w,   // (64,19)
    const float* __restrict__ w1_b,   // (64)
    const float* __restrict__ w2_w,   // (64,64)
    const float* __restrict__ w2_b,   // (64)
    float* __restrict__ emb,          // (G,64)
    int num_graphs)
{
    __shared__ float S[2304];         // 9216 B, reused 4 ways
    __shared__ float dis[32];
    __shared__ float ps[256];

    const int t = threadIdx.x;
    const int l15 = t & 15;
    const int quad = t >> 4;

    // k-validity mask for B-operand repacks (k = quad*8+j < 19)
    float km[8];
    #pragma unroll
    for (int j = 0; j < 8; ++j) km[j] = (quad * 8 + j < GN) ? 1.f : 0.f;

    // ---- weight fragments + biases (once per block) ----
    Frag w1F[4];
    #pragma unroll
    for (int nt = 0; nt < 4; ++nt) {
        int n = nt * 16 + l15;
        #pragma unroll
        for (int p = 0; p < 4; ++p) {
            int k0 = quad * 8 + 2 * p, k1 = k0 + 1;
            float a = (k0 < GN) ? w1_w[n * GN + k0] : 0.f;
            float b = (k1 < GN) ? w1_w[n * GN + k1] : 0.f;
            w1F[nt].i[p] = pkbf(a, b);
        }
    }
    Frag w2F[2][4];
    #pragma unroll
    for (int kt = 0; kt < 2; ++kt)
        #pragma unroll
        for (int nt = 0; nt < 4; ++nt) {
            int n = nt * 16 + l15;
            #pragma unroll
            for (int p = 0; p < 4; ++p) {
                int k = kt * 32 + quad * 8 + 2 * p;
                w2F[kt][nt].i[p] = pkbf(w2_w[n * 64 + k], w2_w[n * 64 + k + 1]);
            }
        }
    float b1v[4], b2v[4];
    #pragma unroll
    for (int nt = 0; nt < 4; ++nt) {
        b1v[nt] = w1_b[nt * 16 + l15];
        b2v[nt] = w2_b[nt * 16 + l15];
    }

    #pragma unroll 1
    for (int g = blockIdx.x; g < num_graphs; g += gridDim.x) {
        const float* Ag = conn + (size_t)g * (GN * GN);

        // zero A region: rows 0..31, cols 0..31 (stride 68)
        #pragma unroll
        for (int i = 0; i < 4; ++i) {
            int s = t + 64 * i;          // 256 float4 slots
            int row = s >> 3, c4 = s & 7;
            f4 z = {0.f, 0.f, 0.f, 0.f};
            *(f4*)&S[row * 68 + c4 * 4] = z;
        }
        // stage A (361 floats)
        #pragma unroll
        for (int i = 0; i < 6; ++i) {
            int e = t + 64 * i;
            if (e < GN * GN) {
                int r = e / GN, c = e - r * GN;
                S[r * 68 + c] = Ag[e];
            }
        }
        __syncthreads();

        // degree -> dis (lanes 0..18), zero pad 19..31
        if (t < 32) {
            float dv = 0.f;
            if (t < GN) {
                float d = 1.0f;   // self loop
                #pragma unroll
                for (int c4 = 0; c4 < 8; ++c4) {
                    f4 v = *(f4*)&S[t * 68 + c4 * 4];
                    d += v.x + v.y + v.z + v.w;
                }
                dv = rsqrtf(d);
            }
            dis[t] = dv;
        }
        __syncthreads();

        // pack aF (raw A) and anF (normalized adjacency), 2 M-tiles
        float dk[8];
        {
            f4 v0 = *(f4*)&dis[quad * 8];
            f4 v1 = *(f4*)&dis[quad * 8 + 4];
            dk[0]=v0.x; dk[1]=v0.y; dk[2]=v0.z; dk[3]=v0.w;
            dk[4]=v1.x; dk[5]=v1.y; dk[6]=v1.z; dk[7]=v1.w;
        }
        Frag aF[2], anF[2];
        #pragma unroll
        for (int mt = 0; mt < 2; ++mt) {
            int m = l15 + 16 * mt;
            float dm = dis[m];
            f4 v0 = *(f4*)&S[m * 68 + quad * 8];
            f4 v1 = *(f4*)&S[m * 68 + quad * 8 + 4];
            float av[8] = {v0.x, v0.y, v0.z, v0.w, v1.x, v1.y, v1.z, v1.w};
            float an[8];
            #pragma unroll
            for (int j = 0; j < 8; ++j) {
                int k = quad * 8 + j;
                an[j] = (av[j] + (m == k ? 1.f : 0.f)) * dm * dk[j];
            }
            #pragma unroll
            for (int p = 0; p < 4; ++p) {
                aF[mt].i[p]  = pkbf(av[2*p], av[2*p+1]);
                anF[mt].i[p] = pkbf(an[2*p], an[2*p+1]);
            }
        }
        __syncthreads();   // done reading A from S

        // MFMA1: H1 = A @ W1^T + b1  -> S transposed (S[n*36 + k])
        #pragma unroll
        for (int mt = 0; mt < 2; ++mt)
            #pragma unroll
            for (int nt = 0; nt < 4; ++nt) {
                float bb = b1v[nt];
                f4 c = {bb, bb, bb, bb};
                c = __builtin_amdgcn_mfma_f32_16x16x32_bf16(aF[mt].s, w1F[nt].s, c, 0, 0, 0);
                int col = nt * 16 + l15;
                #pragma unroll
                for (int r = 0; r < 4; ++r)
                    S[col * 36 + (mt * 16 + quad * 4 + r)] = c[r];
            }
        __syncthreads();

        // pack H1 as B-op: 2 x b128 per n-tile, mask k>=19
        Frag hF[4];
        #pragma unroll
        for (int nt = 0; nt < 4; ++nt) {
            int n = nt * 16 + l15;
            f4 v0 = *(f4*)&S[n * 36 + quad * 8];
            f4 v1 = *(f4*)&S[n * 36 + quad * 8 + 4];
            float vv[8] = {v0.x, v0.y, v0.z, v0.w, v1.x, v1.y, v1.z, v1.w};
            #pragma unroll
            for (int p = 0; p < 4; ++p)
                hF[nt].i[p] = pkbf(vv[2*p] * km[2*p], vv[2*p+1] * km[2*p+1]);
        }
        __syncthreads();   // done reading H1^T

        // MFMA2: X1 = relu(An @ H1) -> S row-major (rows>=19 naturally zero)
        #pragma unroll
        for (int mt = 0; mt < 2; ++mt)
            #pragma unroll
            for (int nt = 0; nt < 4; ++nt) {
                f4 c = {0.f, 0.f, 0.f, 0.f};
                c = __builtin_amdgcn_mfma_f32_16x16x32_bf16(anF[mt].s, hF[nt].s, c, 0, 0, 0);
                int col = nt * 16 + l15;
                #pragma unroll
                for (int r = 0; r < 4; ++r)
                    S[(mt * 16 + quad * 4 + r) * 68 + col] = fmaxf(c[r], 0.f);
            }
        __syncthreads();

        // pack X1 as A-op (2 b128 per (mt,kt))
        Frag xF[2][2];
        #pragma unroll
        for (int mt = 0; mt < 2; ++mt) {
            int m = l15 + 16 * mt;
            #pragma unroll
            for (int kt = 0; kt < 2; ++kt) {
                f4 v0 = *(f4*)&S[m * 68 + kt * 32 + quad * 8];
                f4 v1 = *(f4*)&S[m * 68 + kt * 32 + quad * 8 + 4];
                xF[mt][kt].i[0] = pkbf(v0.x, v0.y);
                xF[mt][kt].i[1] = pkbf(v0.z, v0.w);
                xF[mt][kt].i[2] = pkbf(v1.x, v1.y);
                xF[mt][kt].i[3] = pkbf(v1.z, v1.w);
            }
        }
        __syncthreads();   // done reading X1

        // MFMA3: H2 = X1 @ W2^T + b2 -> S transposed
        #pragma unroll
        for (int mt = 0; mt < 2; ++mt)
            #pragma unroll
            for (int nt = 0; nt < 4; ++nt) {
                float bb = b2v[nt];
                f4 c = {bb, bb, bb, bb};
                c = __builtin_amdgcn_mfma_f32_16x16x32_bf16(xF[mt][0].s, w2F[0][nt].s, c, 0, 0, 0);
                c = __builtin_amdgcn_mfma_f32_16x16x32_bf16(xF[mt][1].s, w2F[1][nt].s, c, 0, 0, 0);
                int col = nt * 16 + l15;
                #pragma unroll
                for (int r = 0; r < 4; ++r)
                    S[col * 36 + (mt * 16 + quad * 4 + r)] = c[r];
            }
        __syncthreads();

        // pack H2 as B-op
        #pragma unroll
        for (int nt = 0; nt < 4; ++nt) {
            int n = nt * 16 + l15;
            f4 v0 = *(f4*)&S[n * 36 + quad * 8];
            f4 v1 = *(f4*)&S[n * 36 + quad * 8 + 4];
            float vv[8] = {v0.x, v0.y, v0.z, v0.w, v1.x, v1.y, v1.z, v1.w};
            #pragma unroll
            for (int p = 0; p < 4; ++p)
                hF[nt].i[p] = pkbf(vv[2*p] * km[2*p], vv[2*p+1] * km[2*p+1]);
        }

        // MFMA4: X2 = relu(An @ H2); column sums -> emb mean
        float cs[4];
        #pragma unroll
        for (int nt = 0; nt < 4; ++nt) cs[nt] = 0.f;
        #pragma unroll
        for (int mt = 0; mt < 2; ++mt)
            #pragma unroll
            for (int nt = 0; nt < 4; ++nt) {
                f4 c = {0.f, 0.f, 0.f, 0.f};
                c = __builtin_amdgcn_mfma_f32_16x16x32_bf16(anF[mt].s, hF[nt].s, c, 0, 0, 0);
                if (mt == 0) {
                    cs[nt] += fmaxf(c[0], 0.f) + fmaxf(c[1], 0.f)
                            + fmaxf(c[2], 0.f) + fmaxf(c[3], 0.f);
                } else if (quad == 0) {   // rows 16,17,18 valid
                    cs[nt] += fmaxf(c[0], 0.f) + fmaxf(c[1], 0.f) + fmaxf(c[2], 0.f);
                }
            }
        __syncthreads();
        #pragma unroll
        for (int nt = 0; nt < 4; ++nt)
            ps[quad * 64 + nt * 16 + l15] = cs[nt];
        __syncthreads();
        float tot = ps[t] + ps[64 + t] + ps[128 + t] + ps[192 + t];
        float mf = (float)mask[g];
        emb[(size_t)g * 64 + t] = tot * (1.f / 19.f) * mf;
        __syncthreads();
    }
}

// ---------------------------------------------------------------------------
// Kernel B: LSTM layer 0.  One block (4 waves) per batch element; thread tid
// owns gate-row tid.  x-matvec for step t+1 computed during step t (its
// uniform s_loads + 64 independent FMAs hide the ds_read/act stalls).
// Single barrier per step via double-buffered gate exchange.
// ---------------------------------------------------------------------------
__global__ __launch_bounds__(256, 1) void lstm_l0(
    const float* __restrict__ x,      // (B*T, 64)
    const float* __restrict__ Wih, const float* __restrict__ Whh,
    const float* __restrict__ bih, const float* __restrict__ bhh,
    float* __restrict__ hseq)         // (B*T, 64)
{
    __shared__ float gs[2][256];
    const int tid = threadIdx.x;
    const int w = tid >> 6, l = tid & 63;
    const int b = blockIdx.x;

    float wi[64], wh[64];
    {
        const float4* p = (const float4*)(Wih + tid * 64);
        const float4* q = (const float4*)(Whh + tid * 64);
        #pragma unroll
        for (int j = 0; j < 16; ++j) {
            ((float4*)wi)[j] = p[j];
            ((float4*)wh)[j] = q[j];
        }
    }
    const float bias = bih[tid] + bhh[tid];
    const float* __restrict__ xb = x + (size_t)b * TT * 64;

    // x-contribution for t = 0
    float xc;
    {
        float n0 = 0.f, n1 = 0.f, n2 = 0.f, n3 = 0.f;
        #pragma unroll
        for (int j = 0; j < 64; j += 4) {
            n0 = fmaf(xb[j],     wi[j],     n0);
            n1 = fmaf(xb[j + 1], wi[j + 1], n1);
            n2 = fmaf(xb[j + 2], wi[j + 2], n2);
            n3 = fmaf(xb[j + 3], wi[j + 3], n3);
        }
        xc = (n0 + n1) + (n2 + n3);
    }

    float h = 0.f, c = 0.f;

    #pragma unroll 1
    for (int t = 0; t < TT; ++t) {
        // prefetch/compute x-contribution for t+1 (independent of h)
        const float* __restrict__ ern = xb + (t + 1 < TT ? t + 1 : TT - 1) * 64;
        float n0 = 0.f, n1 = 0.f, n2 = 0.f, n3 = 0.f;
        #pragma unroll
        for (int j = 0; j < 64; j += 4) {
            n0 = fmaf(ern[j],     wi[j],     n0);
            n1 = fmaf(ern[j + 1], wi[j + 1], n1);
            n2 = fmaf(ern[j + 2], wi[j + 2], n2);
            n3 = fmaf(ern[j + 3], wi[j + 3], n3);
        }
        // h-part (recurrent)
        float a0 = bias + xc, a1 = 0.f, a2 = 0.f, a3 = 0.f;
        #pragma unroll
        for (int j = 0; j < 64; j += 4) {
            a0 = fmaf(rl(h, j),     wh[j],     a0);
            a1 = fmaf(rl(h, j + 1), wh[j + 1], a1);
            a2 = fmaf(rl(h, j + 2), wh[j + 2], a2);
            a3 = fmaf(rl(h, j + 3), wh[j + 3], a3);
        }
        gs[t & 1][tid] = (a0 + a1) + (a2 + a3);
        __syncthreads();
        const float* gp = gs[t & 1];
        float gi = gp[l], gf = gp[64 + l], gg = gp[128 + l], go = gp[192 + l];
        c = sigm(gf) * c + sigm(gi) * tanha(gg);
        h = sigm(go) * tanha(c);
        if (w == 0) hseq[((size_t)b * TT + t) * 64 + l] = h;
        xc = (n0 + n1) + (n2 + n3);
    }
}

// ---------------------------------------------------------------------------
// Kernel C: LSTM layer 1 + FC head.  Same pipeline; captures h at last_idx.
// ---------------------------------------------------------------------------
__global__ __launch_bounds__(256, 1) void lstm_l1_head(
    const float* __restrict__ x,      // (B*T, 64) = h0seq
    const int*   __restrict__ mask,   // (B, T)
    const float* __restrict__ Wih, const float* __restrict__ Whh,
    const float* __restrict__ bih, const float* __restrict__ bhh,
    const float* __restrict__ fc1_w, const float* __restrict__ fc1_b,
    const float* __restrict__ fc2_w, const float* __restrict__ fc2_b,
    float* __restrict__ out)          // (B, 2)
{
    __shared__ float gs[2][256];
    __shared__ int li_s;
    const int tid = threadIdx.x;
    const int w = tid >> 6, l = tid & 63;
    const int b = blockIdx.x;

    float wi[64], wh[64];
    {
        const float4* p = (const float4*)(Wih + tid * 64);
        const float4* q = (const float4*)(Whh + tid * 64);
        #pragma unroll
        for (int j = 0; j < 16; ++j) {
            ((float4*)wi)[j] = p[j];
            ((float4*)wh)[j] = q[j];
        }
    }
    const float bias = bih[tid] + bhh[tid];

    // last_idx = clip(sum(mask)-1, 0, T-1)
    gs[0][tid] = (float)mask[b * TT + tid];
    __syncthreads();
    if (tid == 0) {
        float s = 0.f;
        for (int t = 0; t < TT; ++t) s += gs[0][t];
        int li = (int)s - 1;
        li = li < 0 ? 0 : (li > TT - 1 ? TT - 1 : li);
        li_s = li;
    }
    __syncthreads();
    const int lastidx = li_s;

    const float* __restrict__ xb = x + (size_t)b * TT * 64;

    float xc;
    {
        float n0 = 0.f, n1 = 0.f, n2 = 0.f, n3 = 0.f;
        #pragma unroll
        for (int j = 0; j < 64; j += 4) {
            n0 = fmaf(xb[j],     wi[j],     n0);
            n1 = fmaf(xb[j + 1], wi[j + 1], n1);
            n2 = fmaf(xb[j + 2], wi[j + 2], n2);
            n3 = fmaf(xb[j + 3], wi[j + 3], n3);
        }
        xc = (n0 + n1) + (n2 + n3);
    }

    float h = 0.f, c = 0.f, hl = 0.f;

    #pragma unroll 1
    for (int t = 0; t < TT; ++t) {
        const float* __restrict__ ern = xb + (t + 1 < TT ? t + 1 : TT - 1) * 64;
        float n0 = 0.f, n1 = 0.f, n2 = 0.f, n3 = 0.f;
        #pragma unroll
        for (int j = 0; j < 64; j += 4) {
            n0 = fmaf(ern[j],     wi[j],     n0);
            n1 = fmaf(ern[j + 1], wi[j + 1], n1);
            n2 = fmaf(ern[j + 2], wi[j + 2], n2);
            n3 = fmaf(ern[j + 3], wi[j + 3], n3);
        }
        float a0 = bias + xc, a1 = 0.f, a2 = 0.f, a3 = 0.f;
        #pragma unroll
        for (int j = 0; j < 64; j += 4) {
            a0 = fmaf(rl(h, j),     wh[j],     a0);
            a1 = fmaf(rl(h, j + 1), wh[j + 1], a1);
            a2 = fmaf(rl(h, j + 2), wh[j + 2], a2);
            a3 = fmaf(rl(h, j + 3), wh[j + 3], a3);
        }
        gs[t & 1][tid] = (a0 + a1) + (a2 + a3);
        __syncthreads();
        const float* gp = gs[t & 1];
        float gi = gp[l], gf = gp[64 + l], gg = gp[128 + l], go = gp[192 + l];
        c = sigm(gf) * c + sigm(gi) * tanha(gg);
        h = sigm(go) * tanha(c);
        if (t == lastidx) hl = h;
        xc = (n0 + n1) + (n2 + n3);
    }

    // head: fc1 (64->32) relu, fc2 (32->2); wave 0 only
    __syncthreads();
    if (w == 0 && l < 32) {
        float acc = fc1_b[l];
        const float* fw = fc1_w + l * 64;
        #pragma unroll
        for (int j = 0; j < 64; ++j)
            acc = fmaf(fw[j], rl(hl, j), acc);
        gs[0][l] = fmaxf(acc, 0.f);
    }
    __syncthreads();
    if (w == 0 && l < 2) {
        float acc = fc2_b[l];
        #pragma unroll
        for (int j = 0; j < 32; ++j)
            acc = fmaf(fc2_w[l * 32 + j], gs[0][j], acc);
        out[b * 2 + l] = acc;
    }
}

// ---------------------------------------------------------------------------
extern "C" void kernel_launch(void* const* d_in, const int* in_sizes, int n_in,
                              void* d_out, int out_size, void* d_ws, size_t ws_size,
                              hipStream_t stream)
{
    const float* conn  = (const float*)d_in[0];
    const int*   mask  = (const int*)  d_in[1];
    const float* w1_w  = (const float*)d_in[2];
    const float* w1_b  = (const float*)d_in[3];
    const float* w2_w  = (const float*)d_in[4];
    const float* w2_b  = (const float*)d_in[5];
    const float* Wih0  = (const float*)d_in[6];
    const float* Whh0  = (const float*)d_in[7];
    const float* bih0  = (const float*)d_in[8];
    const float* bhh0  = (const float*)d_in[9];
    const float* Wih1  = (const float*)d_in[10];
    const float* Whh1  = (const float*)d_in[11];
    const float* bih1  = (const float*)d_in[12];
    const float* bhh1  = (const float*)d_in[13];
    const float* fc1_w = (const float*)d_in[14];
    const float* fc1_b = (const float*)d_in[15];
    const float* fc2_w = (const float*)d_in[16];
    const float* fc2_b = (const float*)d_in[17];

    float* out = (float*)d_out;
    float* emb   = (float*)d_ws;                         // 16.8 MB
    float* h0seq = (float*)d_ws + (size_t)BB * TT * 64;  // +16.8 MB

    const int num_graphs = BB * TT;

    encoder_mfma<<<8192, 64, 0, stream>>>(
        conn, mask, w1_w, w1_b, w2_w, w2_b, emb, num_graphs);

    lstm_l0<<<BB, 256, 0, stream>>>(emb, Wih0, Whh0, bih0, bhh0, h0seq);

    lstm_l1_head<<<BB, 256, 0, stream>>>(
        h0seq, mask, Wih1, Whh1, bih1, bhh1,
        fc1_w, fc1_b, fc2_w, fc2_b, out);
}

// Round 4
// 600.705 us; speedup vs baseline: 2.8539x; 1.4715x over previous
//
#include <hip/hip_runtime.h>
#include <hip/hip_bf16.h>
#include <math.h>

#define GN 19            // graph nodes
#define BB 256
#define TT 256

typedef short short8 __attribute__((ext_vector_type(8)));
typedef float f4 __attribute__((ext_vector_type(4)));

union Frag { int i[4]; short8 s; };

// wave-local LDS ordering fence: wait LDS ops, NO vmcnt drain, no barrier.
#define LWAIT() __asm__ volatile("s_waitcnt lgkmcnt(0)" ::: "memory")
// workgroup barrier WITHOUT vmcnt(0) drain: global loads/stores stay in flight.
#define WGBAR() __asm__ volatile("s_waitcnt lgkmcnt(0)\ns_barrier" ::: "memory")

// packed RNE float pair -> bf16 pair (v_cvt_pk_bf16_f32 on gfx950)
__device__ __forceinline__ int pkbf(float a, float b) {
    __hip_bfloat162 h2 = __float22bfloat162_rn(make_float2(a, b));
    union { __hip_bfloat162 h; int i; } u; u.h = h2; return u.i;
}

__device__ __forceinline__ float rl(float v, int j) {
    return __int_as_float(__builtin_amdgcn_readlane(__float_as_int(v), j));
}
__device__ __forceinline__ float fexp2(float x) { return __builtin_amdgcn_exp2f(x); }
__device__ __forceinline__ float frcp(float x)  { return __builtin_amdgcn_rcpf(x); }
__device__ __forceinline__ float sigm(float x)  { return frcp(1.f + fexp2(-1.4426950408889634f * x)); }
__device__ __forceinline__ float tanha(float x) { float e = fexp2(2.8853900817779268f * x); return 1.f - 2.f * frcp(e + 1.f); }

// ---------------------------------------------------------------------------
// Kernel A: graph encoder via bf16 MFMA (16x16x32).  One wave per block,
// grid-stride over graphs.  1-wave workgroup => no s_barrier needed at all;
// phase ordering via lgkmcnt waits only (global loads stay in flight).
// Next graph's A is register-prefetched during the current graph's pipeline.
// ---------------------------------------------------------------------------
__global__ __launch_bounds__(64) void encoder_mfma(
    const float* __restrict__ conn,   // (G,19,19)
    const int*   __restrict__ mask,   // (G)
    const float* __restrict__ w1_w,   // (64,19)
    const float* __restrict__ w1_b,   // (64)
    const float* __restrict__ w2_w,   // (64,64)
    const float* __restrict__ w2_b,   // (64)
    float* __restrict__ emb,          // (G,64)
    int num_graphs)
{
    __shared__ float S[2304];         // 9216 B, reused 4 ways
    __shared__ float dis[32];
    __shared__ float ps[256];

    const int t = threadIdx.x;
    const int l15 = t & 15;
    const int quad = t >> 4;

    // k-validity mask for B-operand repacks (k = quad*8+j < 19)
    float km[8];
    #pragma unroll
    for (int j = 0; j < 8; ++j) km[j] = (quad * 8 + j < GN) ? 1.f : 0.f;

    // loop-invariant scatter coords for A staging (e = t + 64*i)
    int rr[6], cc[6];
    #pragma unroll
    for (int i = 0; i < 6; ++i) {
        int e = t + 64 * i;
        rr[i] = e / GN;
        cc[i] = e - rr[i] * GN;
    }

    // ---- weight fragments + biases (once per block) ----
    Frag w1F[4];
    #pragma unroll
    for (int nt = 0; nt < 4; ++nt) {
        int n = nt * 16 + l15;
        #pragma unroll
        for (int p = 0; p < 4; ++p) {
            int k0 = quad * 8 + 2 * p, k1 = k0 + 1;
            float a = (k0 < GN) ? w1_w[n * GN + k0] : 0.f;
            float b = (k1 < GN) ? w1_w[n * GN + k1] : 0.f;
            w1F[nt].i[p] = pkbf(a, b);
        }
    }
    Frag w2F[2][4];
    #pragma unroll
    for (int kt = 0; kt < 2; ++kt)
        #pragma unroll
        for (int nt = 0; nt < 4; ++nt) {
            int n = nt * 16 + l15;
            #pragma unroll
            for (int p = 0; p < 4; ++p) {
                int k = kt * 32 + quad * 8 + 2 * p;
                w2F[kt][nt].i[p] = pkbf(w2_w[n * 64 + k], w2_w[n * 64 + k + 1]);
            }
        }
    float b1v[4], b2v[4];
    #pragma unroll
    for (int nt = 0; nt < 4; ++nt) {
        b1v[nt] = w1_b[nt * 16 + l15];
        b2v[nt] = w2_b[nt * 16 + l15];
    }

    // prologue: prefetch first graph's A into registers
    float pf[6];
    {
        int g0 = blockIdx.x < num_graphs ? blockIdx.x : 0;
        const float* Ag = conn + (size_t)g0 * (GN * GN);
        #pragma unroll
        for (int i = 0; i < 6; ++i) {
            int e = t + 64 * i;
            if (e < GN * GN) pf[i] = Ag[e];
        }
    }

    #pragma unroll 1
    for (int g = blockIdx.x; g < num_graphs; g += gridDim.x) {
        // zero A region: rows 0..31, cols 0..31 (stride 68)
        #pragma unroll
        for (int i = 0; i < 4; ++i) {
            int s = t + 64 * i;          // 256 float4 slots
            int row = s >> 3, c4 = s & 7;
            f4 z = {0.f, 0.f, 0.f, 0.f};
            *(f4*)&S[row * 68 + c4 * 4] = z;
        }
        LWAIT();   // zeros before scatter (same addresses)
        // scatter prefetched A (361 floats)
        #pragma unroll
        for (int i = 0; i < 6; ++i) {
            if (t + 64 * i < GN * GN) S[rr[i] * 68 + cc[i]] = pf[i];
        }
        // issue prefetch for the NEXT graph (stays in flight all pipeline)
        {
            int gn = g + gridDim.x;
            const float* Ag = conn + (size_t)(gn < num_graphs ? gn : g) * (GN * GN);
            #pragma unroll
            for (int i = 0; i < 6; ++i) {
                int e = t + 64 * i;
                if (e < GN * GN) pf[i] = Ag[e];
            }
        }
        LWAIT();   // staging visible

        // degree -> dis (lanes 0..18), zero pad 19..31
        if (t < 32) {
            float dv = 0.f;
            if (t < GN) {
                float d = 1.0f;   // self loop
                #pragma unroll
                for (int c4 = 0; c4 < 8; ++c4) {
                    f4 v = *(f4*)&S[t * 68 + c4 * 4];
                    d += v.x + v.y + v.z + v.w;
                }
                dv = rsqrtf(d);
            }
            dis[t] = dv;
        }
        LWAIT();

        // pack aF (raw A) and anF (normalized adjacency), 2 M-tiles
        float dk[8];
        {
            f4 v0 = *(f4*)&dis[quad * 8];
            f4 v1 = *(f4*)&dis[quad * 8 + 4];
            dk[0]=v0.x; dk[1]=v0.y; dk[2]=v0.z; dk[3]=v0.w;
            dk[4]=v1.x; dk[5]=v1.y; dk[6]=v1.z; dk[7]=v1.w;
        }
        Frag aF[2], anF[2];
        #pragma unroll
        for (int mt = 0; mt < 2; ++mt) {
            int m = l15 + 16 * mt;
            float dm = dis[m];
            f4 v0 = *(f4*)&S[m * 68 + quad * 8];
            f4 v1 = *(f4*)&S[m * 68 + quad * 8 + 4];
            float av[8] = {v0.x, v0.y, v0.z, v0.w, v1.x, v1.y, v1.z, v1.w};
            float an[8];
            #pragma unroll
            for (int j = 0; j < 8; ++j) {
                int k = quad * 8 + j;
                an[j] = (av[j] + (m == k ? 1.f : 0.f)) * dm * dk[j];
            }
            #pragma unroll
            for (int p = 0; p < 4; ++p) {
                aF[mt].i[p]  = pkbf(av[2*p], av[2*p+1]);
                anF[mt].i[p] = pkbf(an[2*p], an[2*p+1]);
            }
        }
        LWAIT();   // A reads done before H1^T overwrites S

        // MFMA1: H1 = A @ W1^T + b1  -> S transposed (S[n*36 + k])
        #pragma unroll
        for (int mt = 0; mt < 2; ++mt)
            #pragma unroll
            for (int nt = 0; nt < 4; ++nt) {
                float bb = b1v[nt];
                f4 c = {bb, bb, bb, bb};
                c = __builtin_amdgcn_mfma_f32_16x16x32_bf16(aF[mt].s, w1F[nt].s, c, 0, 0, 0);
                int col = nt * 16 + l15;
                #pragma unroll
                for (int r = 0; r < 4; ++r)
                    S[col * 36 + (mt * 16 + quad * 4 + r)] = c[r];
            }
        LWAIT();

        // pack H1 as B-op: 2 x b128 per n-tile, mask k>=19
        Frag hF[4];
        #pragma unroll
        for (int nt = 0; nt < 4; ++nt) {
            int n = nt * 16 + l15;
            f4 v0 = *(f4*)&S[n * 36 + quad * 8];
            f4 v1 = *(f4*)&S[n * 36 + quad * 8 + 4];
            float vv[8] = {v0.x, v0.y, v0.z, v0.w, v1.x, v1.y, v1.z, v1.w};
            #pragma unroll
            for (int p = 0; p < 4; ++p)
                hF[nt].i[p] = pkbf(vv[2*p] * km[2*p], vv[2*p+1] * km[2*p+1]);
        }
        LWAIT();   // H1^T reads done

        // MFMA2: X1 = relu(An @ H1) -> S row-major (rows>=19 naturally zero)
        #pragma unroll
        for (int mt = 0; mt < 2; ++mt)
            #pragma unroll
            for (int nt = 0; nt < 4; ++nt) {
                f4 c = {0.f, 0.f, 0.f, 0.f};
                c = __builtin_amdgcn_mfma_f32_16x16x32_bf16(anF[mt].s, hF[nt].s, c, 0, 0, 0);
                int col = nt * 16 + l15;
                #pragma unroll
                for (int r = 0; r < 4; ++r)
                    S[(mt * 16 + quad * 4 + r) * 68 + col] = fmaxf(c[r], 0.f);
            }
        LWAIT();

        // pack X1 as A-op (2 b128 per (mt,kt))
        Frag xF[2][2];
        #pragma unroll
        for (int mt = 0; mt < 2; ++mt) {
            int m = l15 + 16 * mt;
            #pragma unroll
            for (int kt = 0; kt < 2; ++kt) {
                f4 v0 = *(f4*)&S[m * 68 + kt * 32 + quad * 8];
                f4 v1 = *(f4*)&S[m * 68 + kt * 32 + quad * 8 + 4];
                xF[mt][kt].i[0] = pkbf(v0.x, v0.y);
                xF[mt][kt].i[1] = pkbf(v0.z, v0.w);
                xF[mt][kt].i[2] = pkbf(v1.x, v1.y);
                xF[mt][kt].i[3] = pkbf(v1.z, v1.w);
            }
        }
        LWAIT();   // X1 reads done

        // MFMA3: H2 = X1 @ W2^T + b2 -> S transposed
        #pragma unroll
        for (int mt = 0; mt < 2; ++mt)
            #pragma unroll
            for (int nt = 0; nt < 4; ++nt) {
                float bb = b2v[nt];
                f4 c = {bb, bb, bb, bb};
                c = __builtin_amdgcn_mfma_f32_16x16x32_bf16(xF[mt][0].s, w2F[0][nt].s, c, 0, 0, 0);
                c = __builtin_amdgcn_mfma_f32_16x16x32_bf16(xF[mt][1].s, w2F[1][nt].s, c, 0, 0, 0);
                int col = nt * 16 + l15;
                #pragma unroll
                for (int r = 0; r < 4; ++r)
                    S[col * 36 + (mt * 16 + quad * 4 + r)] = c[r];
            }
        LWAIT();

        // pack H2 as B-op
        #pragma unroll
        for (int nt = 0; nt < 4; ++nt) {
            int n = nt * 16 + l15;
            f4 v0 = *(f4*)&S[n * 36 + quad * 8];
            f4 v1 = *(f4*)&S[n * 36 + quad * 8 + 4];
            float vv[8] = {v0.x, v0.y, v0.z, v0.w, v1.x, v1.y, v1.z, v1.w};
            #pragma unroll
            for (int p = 0; p < 4; ++p)
                hF[nt].i[p] = pkbf(vv[2*p] * km[2*p], vv[2*p+1] * km[2*p+1]);
        }

        // MFMA4: X2 = relu(An @ H2); column sums -> emb mean
        float cs[4];
        #pragma unroll
        for (int nt = 0; nt < 4; ++nt) cs[nt] = 0.f;
        #pragma unroll
        for (int mt = 0; mt < 2; ++mt)
            #pragma unroll
            for (int nt = 0; nt < 4; ++nt) {
                f4 c = {0.f, 0.f, 0.f, 0.f};
                c = __builtin_amdgcn_mfma_f32_16x16x32_bf16(anF[mt].s, hF[nt].s, c, 0, 0, 0);
                if (mt == 0) {
                    cs[nt] += fmaxf(c[0], 0.f) + fmaxf(c[1], 0.f)
                            + fmaxf(c[2], 0.f) + fmaxf(c[3], 0.f);
                } else if (quad == 0) {   // rows 16,17,18 valid
                    cs[nt] += fmaxf(c[0], 0.f) + fmaxf(c[1], 0.f) + fmaxf(c[2], 0.f);
                }
            }
        #pragma unroll
        for (int nt = 0; nt < 4; ++nt)
            ps[quad * 64 + nt * 16 + l15] = cs[nt];
        LWAIT();
        float tot = ps[t] + ps[64 + t] + ps[128 + t] + ps[192 + t];
        float mf = (float)mask[g];
        emb[(size_t)g * 64 + t] = tot * (1.f / 19.f) * mf;
        LWAIT();   // ps reads done before next iteration reuses LDS
    }
}

// ---------------------------------------------------------------------------
// Kernel B: LSTM layer 0.  One block (4 waves) per batch element; thread tid
// owns gate-row tid.  Raw s_barrier (no vmcnt drain) keeps the next x-row
// loads in flight across the step.  Step order: issue loads(t+1) -> h-part
// FMAs -> gate exchange/activation -> x-FMAs(t+1) (loads covered ~full step).
// ---------------------------------------------------------------------------
__global__ __launch_bounds__(256, 1) void lstm_l0(
    const float* __restrict__ x,      // (B*T, 64)
    const float* __restrict__ Wih, const float* __restrict__ Whh,
    const float* __restrict__ bih, const float* __restrict__ bhh,
    float* __restrict__ hseq)         // (B*T, 64)
{
    __shared__ float gs[2][256];
    const int tid = threadIdx.x;
    const int w = tid >> 6, l = tid & 63;
    const int b = blockIdx.x;

    float wi[64], wh[64];
    {
        const float4* p = (const float4*)(Wih + tid * 64);
        const float4* q = (const float4*)(Whh + tid * 64);
        #pragma unroll
        for (int j = 0; j < 16; ++j) {
            ((float4*)wi)[j] = p[j];
            ((float4*)wh)[j] = q[j];
        }
    }
    const float bias = bih[tid] + bhh[tid];
    const float* __restrict__ xb = x + (size_t)b * TT * 64;

    // x-contribution for t = 0
    float xc;
    {
        float n0 = 0.f, n1 = 0.f, n2 = 0.f, n3 = 0.f;
        #pragma unroll
        for (int j = 0; j < 64; j += 4) {
            n0 = fmaf(xb[j],     wi[j],     n0);
            n1 = fmaf(xb[j + 1], wi[j + 1], n1);
            n2 = fmaf(xb[j + 2], wi[j + 2], n2);
            n3 = fmaf(xb[j + 3], wi[j + 3], n3);
        }
        xc = (n0 + n1) + (n2 + n3);
    }

    float h = 0.f, c = 0.f;

    #pragma unroll 1
    for (int t = 0; t < TT; ++t) {
        // issue raw loads of row t+1 NOW (consumed only after activation)
        const f4* __restrict__ ern = (const f4*)(xb + (t + 1 < TT ? t + 1 : TT - 1) * 64);
        f4 xr[16];
        #pragma unroll
        for (int k = 0; k < 16; ++k) xr[k] = ern[k];

        // h-part (recurrent critical path)
        float a0 = bias + xc, a1 = 0.f, a2 = 0.f, a3 = 0.f;
        #pragma unroll
        for (int j = 0; j < 64; j += 4) {
            a0 = fmaf(rl(h, j),     wh[j],     a0);
            a1 = fmaf(rl(h, j + 1), wh[j + 1], a1);
            a2 = fmaf(rl(h, j + 2), wh[j + 2], a2);
            a3 = fmaf(rl(h, j + 3), wh[j + 3], a3);
        }
        gs[t & 1][tid] = (a0 + a1) + (a2 + a3);
        WGBAR();
        const float* gp = gs[t & 1];
        float gi = gp[l], gf = gp[64 + l], gg = gp[128 + l], go = gp[192 + l];
        c = sigm(gf) * c + sigm(gi) * tanha(gg);
        h = sigm(go) * tanha(c);
        if (w == 0) hseq[((size_t)b * TT + t) * 64 + l] = h;

        // x-contribution for t+1 from prefetched regs
        float n0 = 0.f, n1 = 0.f, n2 = 0.f, n3 = 0.f;
        #pragma unroll
        for (int k = 0; k < 16; ++k) {
            f4 v = xr[k];
            n0 = fmaf(v.x, wi[4*k],     n0);
            n1 = fmaf(v.y, wi[4*k + 1], n1);
            n2 = fmaf(v.z, wi[4*k + 2], n2);
            n3 = fmaf(v.w, wi[4*k + 3], n3);
        }
        xc = (n0 + n1) + (n2 + n3);
    }
}

// ---------------------------------------------------------------------------
// Kernel C: LSTM layer 1 + FC head.  Same pipeline; captures h at last_idx.
// ---------------------------------------------------------------------------
__global__ __launch_bounds__(256, 1) void lstm_l1_head(
    const float* __restrict__ x,      // (B*T, 64) = h0seq
    const int*   __restrict__ mask,   // (B, T)
    const float* __restrict__ Wih, const float* __restrict__ Whh,
    const float* __restrict__ bih, const float* __restrict__ bhh,
    const float* __restrict__ fc1_w, const float* __restrict__ fc1_b,
    const float* __restrict__ fc2_w, const float* __restrict__ fc2_b,
    float* __restrict__ out)          // (B, 2)
{
    __shared__ float gs[2][256];
    __shared__ int li_s;
    const int tid = threadIdx.x;
    const int w = tid >> 6, l = tid & 63;
    const int b = blockIdx.x;

    float wi[64], wh[64];
    {
        const float4* p = (const float4*)(Wih + tid * 64);
        const float4* q = (const float4*)(Whh + tid * 64);
        #pragma unroll
        for (int j = 0; j < 16; ++j) {
            ((float4*)wi)[j] = p[j];
            ((float4*)wh)[j] = q[j];
        }
    }
    const float bias = bih[tid] + bhh[tid];

    // last_idx = clip(sum(mask)-1, 0, T-1)
    gs[0][tid] = (float)mask[b * TT + tid];
    __syncthreads();
    if (tid == 0) {
        float s = 0.f;
        for (int t = 0; t < TT; ++t) s += gs[0][t];
        int li = (int)s - 1;
        li = li < 0 ? 0 : (li > TT - 1 ? TT - 1 : li);
        li_s = li;
    }
    __syncthreads();
    const int lastidx = li_s;

    const float* __restrict__ xb = x + (size_t)b * TT * 64;

    float xc;
    {
        float n0 = 0.f, n1 = 0.f, n2 = 0.f, n3 = 0.f;
        #pragma unroll
        for (int j = 0; j < 64; j += 4) {
            n0 = fmaf(xb[j],     wi[j],     n0);
            n1 = fmaf(xb[j + 1], wi[j + 1], n1);
            n2 = fmaf(xb[j + 2], wi[j + 2], n2);
            n3 = fmaf(xb[j + 3], wi[j + 3], n3);
        }
        xc = (n0 + n1) + (n2 + n3);
    }

    float h = 0.f, c = 0.f, hl = 0.f;

    #pragma unroll 1
    for (int t = 0; t < TT; ++t) {
        const f4* __restrict__ ern = (const f4*)(xb + (t + 1 < TT ? t + 1 : TT - 1) * 64);
        f4 xr[16];
        #pragma unroll
        for (int k = 0; k < 16; ++k) xr[k] = ern[k];

        float a0 = bias + xc, a1 = 0.f, a2 = 0.f, a3 = 0.f;
        #pragma unroll
        for (int j = 0; j < 64; j += 4) {
            a0 = fmaf(rl(h, j),     wh[j],     a0);
            a1 = fmaf(rl(h, j + 1), wh[j + 1], a1);
            a2 = fmaf(rl(h, j + 2), wh[j + 2], a2);
            a3 = fmaf(rl(h, j + 3), wh[j + 3], a3);
        }
        gs[t & 1][tid] = (a0 + a1) + (a2 + a3);
        WGBAR();
        const float* gp = gs[t & 1];
        float gi = gp[l], gf = gp[64 + l], gg = gp[128 + l], go = gp[192 + l];
        c = sigm(gf) * c + sigm(gi) * tanha(gg);
        h = sigm(go) * tanha(c);
        if (t == lastidx) hl = h;

        float n0 = 0.f, n1 = 0.f, n2 = 0.f, n3 = 0.f;
        #pragma unroll
        for (int k = 0; k < 16; ++k) {
            f4 v = xr[k];
            n0 = fmaf(v.x, wi[4*k],     n0);
            n1 = fmaf(v.y, wi[4*k + 1], n1);
            n2 = fmaf(v.z, wi[4*k + 2], n2);
            n3 = fmaf(v.w, wi[4*k + 3], n3);
        }
        xc = (n0 + n1) + (n2 + n3);
    }

    // head: fc1 (64->32) relu, fc2 (32->2); wave 0 only
    __syncthreads();
    if (w == 0 && l < 32) {
        float acc = fc1_b[l];
        const float* fw = fc1_w + l * 64;
        #pragma unroll
        for (int j = 0; j < 64; ++j)
            acc = fmaf(fw[j], rl(hl, j), acc);
        gs[0][l] = fmaxf(acc, 0.f);
    }
    __syncthreads();
    if (w == 0 && l < 2) {
        float acc = fc2_b[l];
        #pragma unroll
        for (int j = 0; j < 32; ++j)
            acc = fmaf(fc2_w[l * 32 + j], gs[0][j], acc);
        out[b * 2 + l] = acc;
    }
}

// ---------------------------------------------------------------------------
extern "C" void kernel_launch(void* const* d_in, const int* in_sizes, int n_in,
                              void* d_out, int out_size, void* d_ws, size_t ws_size,
                              hipStream_t stream)
{
    const float* conn  = (const float*)d_in[0];
    const int*   mask  = (const int*)  d_in[1];
    const float* w1_w  = (const float*)d_in[2];
    const float* w1_b  = (const float*)d_in[3];
    const float* w2_w  = (const float*)d_in[4];
    const float* w2_b  = (const float*)d_in[5];
    const float* Wih0  = (const float*)d_in[6];
    const float* Whh0  = (const float*)d_in[7];
    const float* bih0  = (const float*)d_in[8];
    const float* bhh0  = (const float*)d_in[9];
    const float* Wih1  = (const float*)d_in[10];
    const float* Whh1  = (const float*)d_in[11];
    const float* bih1  = (const float*)d_in[12];
    const float* bhh1  = (const float*)d_in[13];
    const float* fc1_w = (const float*)d_in[14];
    const float* fc1_b = (const float*)d_in[15];
    const float* fc2_w = (const float*)d_in[16];
    const float* fc2_b = (const float*)d_in[17];

    float* out = (float*)d_out;
    float* emb   = (float*)d_ws;                         // 16.8 MB
    float* h0seq = (float*)d_ws + (size_t)BB * TT * 64;  // +16.8 MB

    const int num_graphs = BB * TT;

    encoder_mfma<<<8192, 64, 0, stream>>>(
        conn, mask, w1_w, w1_b, w2_w, w2_b, emb, num_graphs);

    lstm_l0<<<BB, 256, 0, stream>>>(emb, Wih0, Whh0, bih0, bhh0, h0seq);

    lstm_l1_head<<<BB, 256, 0, stream>>>(
        h0seq, mask, Wih1, Whh1, bih1, bhh1,
        fc1_w, fc1_b, fc2_w, fc2_b, out);
}